// Round 19
// baseline (32.762 us; speedup 1.0000x reference)
//
#include <hip/hip_runtime.h>

typedef float v4f __attribute__((ext_vector_type(4)));

#define NPTS   4096
#define NZ     16                  // B * 2 passes
#define QPT    16                  // queries per thread: one block covers all 4096
#define TPB    256
#define CHUNK  128                 // points staged per block
#define NGRP   (CHUNK / 4)         // 32 groups of 4 points
#define NCHUNK (NPTS / CHUNK)      // 32

// NOTE: no inline-asm in the hot loop. r18 used asm("v_min3_f32") per 2 pairs;
// 56 asm fragments/group can fragment clang's scheduling regions and serialize
// q-iterations (dep-latency-bound signature: ~4.7cy/instr observed vs 2cy
// issue). fminf chains give the scheduler full freedom (clang fuses nested
// fminf to v_min3_f32 where profitable).

__global__ __launch_bounds__(TPB, 2) void min_kernel(const float* __restrict__ preds,
                                                     const float* __restrict__ gts,
                                                     float* __restrict__ partial) {
    const int z    = blockIdx.y;
    const int b    = z >> 1;
    const int pass = z & 1;
    const int tid  = threadIdx.x;

    const float* pts = pass ? preds : gts;   // pass0: min over gts (per pred)
    const float* qrs = pass ? gts   : preds; // pass1: min over preds (per gt)

    __shared__ float SX[CHUNK], SY[CHUNK], SZ[CHUNK], SW[CHUNK];

    // ---- stage CHUNK points, SoA (+|p|^2) ----
    {
        const float* pb = pts + ((size_t)b * NPTS + blockIdx.x * CHUNK) * 3;
        if (tid < CHUNK) {
            float x  = pb[tid * 3 + 0];
            float y  = pb[tid * 3 + 1];
            float zz = pb[tid * 3 + 2];
            SX[tid] = x;
            SY[tid] = y;
            SZ[tid] = zz;
            SW[tid] = fmaf(x, x, fmaf(y, y, zz * zz));
        }
    }

    // ---- per-thread queries (16: whole 4096 covered by the block) ----
    const float* qb = qrs + (size_t)b * NPTS * 3;
    float ax[QPT], ay[QPT], az[QPT], R[QPT], acc[QPT];
#pragma unroll
    for (int q = 0; q < QPT; ++q) {
        int   j  = q * TPB + tid;
        float qx = qb[j * 3 + 0];
        float qy = qb[j * 3 + 1];
        float qz = qb[j * 3 + 2];
        R[q]  = fmaf(qx, qx, fmaf(qy, qy, qz * qz));
        ax[q] = -2.0f * qx;
        ay[q] = -2.0f * qy;
        az[q] = -2.0f * qz;
        acc[q] = 3.4e38f;
    }
    __syncthreads();

    const v4f* SXv = (const v4f*)SX;
    const v4f* SYv = (const v4f*)SY;
    const v4f* SZv = (const v4f*)SZ;
    const v4f* SWv = (const v4f*)SW;

    // ---- main loop with depth-1 prefetch: load g+1 before computing g ----
    v4f Xn = SXv[0], Yn = SYv[0], Zn = SZv[0], Wn = SWv[0];
#pragma unroll 1
    for (int g = 0; g < NGRP; ++g) {
        const v4f X = Xn, Y = Yn, Z = Zn, W = Wn;
        const int gn = (g + 1) & (NGRP - 1);   // wrap: benign re-read, no branch
        Xn = SXv[gn]; Yn = SYv[gn]; Zn = SZv[gn]; Wn = SWv[gn];
#pragma unroll
        for (int q = 0; q < QPT; ++q) {
            float t0 = fmaf(X.x, ax[q], fmaf(Y.x, ay[q], fmaf(Z.x, az[q], W.x)));
            float t1 = fmaf(X.y, ax[q], fmaf(Y.y, ay[q], fmaf(Z.y, az[q], W.y)));
            float t2 = fmaf(X.z, ax[q], fmaf(Y.z, ay[q], fmaf(Z.z, az[q], W.z)));
            float t3 = fmaf(X.w, ax[q], fmaf(Y.w, ay[q], fmaf(Z.w, az[q], W.w)));
            acc[q] = fminf(acc[q], fminf(fminf(t0, t1), fminf(t2, t3)));
        }
    }

    // ---- store per-(z,chunk) partial mins (unique slots, coalesced) ----
    float* dst = partial + ((size_t)z * NCHUNK + blockIdx.x) * NPTS;
#pragma unroll
    for (int q = 0; q < QPT; ++q) {
        dst[q * TPB + tid] = R[q] + acc[q];
    }
}

// min over the NCHUNK partials per query, huber, block partial-sum.
__global__ __launch_bounds__(256) void huber_kernel(const float* __restrict__ partial,
                                                    const float* __restrict__ cp,
                                                    float* __restrict__ bp) {
    const int s = blockIdx.x * 256 + threadIdx.x;   // [0, NZ*NPTS)
    const int z = s >> 12, j = s & (NPTS - 1);
    const float* p = partial + (size_t)z * NCHUNK * NPTS + j;
    float m = 3.4e38f;
#pragma unroll
    for (int c = 0; c < NCHUNK; ++c) m = fminf(m, p[(size_t)c * NPTS]);
    const float cc = cp[0];
    float h = (m < cc) ? (0.5f * m * m) : fmaf(cc, m, -0.5f * cc * cc);
    for (int off = 32; off > 0; off >>= 1) h += __shfl_down(h, off, 64);
    __shared__ float ls[4];
    if ((threadIdx.x & 63) == 0) ls[threadIdx.x >> 6] = h;
    __syncthreads();
    if (threadIdx.x == 0) bp[blockIdx.x] = ls[0] + ls[1] + ls[2] + ls[3];
}

__global__ __launch_bounds__(256) void final_kernel(const float* __restrict__ bp,
                                                    float* __restrict__ out) {
    float a = bp[threadIdx.x];   // exactly 256 block partials
    for (int off = 32; off > 0; off >>= 1) a += __shfl_down(a, off, 64);
    __shared__ float ls[4];
    if ((threadIdx.x & 63) == 0) ls[threadIdx.x >> 6] = a;
    __syncthreads();
    if (threadIdx.x == 0) out[0] = ls[0] + ls[1] + ls[2] + ls[3];
}

extern "C" void kernel_launch(void* const* d_in, const int* in_sizes, int n_in,
                              void* d_out, int out_size, void* d_ws, size_t ws_size,
                              hipStream_t stream) {
    const float* preds = (const float*)d_in[0];  // [8, 4096, 3]
    const float* gts   = (const float*)d_in[1];  // [8, 4096, 3]
    const float* cp    = (const float*)d_in[2];  // [1]
    float* out = (float*)d_out;

    float* partial = (float*)d_ws;                           // [NZ][NCHUNK][NPTS] = 8 MB
    float* bp      = partial + (size_t)NZ * NCHUNK * NPTS;   // [256]

    dim3 gm(NCHUNK, NZ);   // (32, 16) = 512 blocks
    min_kernel<<<gm, TPB, 0, stream>>>(preds, gts, partial);

    huber_kernel<<<(NZ * NPTS) / 256, 256, 0, stream>>>(partial, cp, bp);
    final_kernel<<<1, 256, 0, stream>>>(bp, out);
}